// Round 8
// baseline (220.566 us; speedup 1.0000x reference)
//
#include <hip/hip_runtime.h>

#define HEADS 64
#define SEQ 2048
#define DIM 64
#define BR 256          // q rows per block (32 per wave, 8 waves)
#define BC 64           // keys per blob
#define NB (SEQ / BC)   // 32 blobs
#define NPAIR (NB / 2)  // 16 loop trips, 2 blobs (128 keys) each
#define TILE_U16 (BC * DIM)  // 4096 u16 = 8192 B per blob

typedef __attribute__((ext_vector_type(4))) float f32x4;
typedef __attribute__((ext_vector_type(8))) short s16x8;
typedef __attribute__((ext_vector_type(4))) unsigned int u32x4;

// pack two fp32 -> two bf16 (round-half-up) in one v_perm
__device__ __forceinline__ unsigned pack2(float lo, float hi) {
  unsigned a = __builtin_bit_cast(unsigned, hi) + 0x8000u;
  unsigned b = __builtin_bit_cast(unsigned, lo) + 0x8000u;
  return __builtin_amdgcn_perm(a, b, 0x07060302u);
}

// single-instruction packed fp32->bf16 (RNE)
__device__ __forceinline__ unsigned cvt_pk_bf16(float lo, float hi) {
  unsigned r;
  asm("v_cvt_pk_bf16_f32 %0, %1, %2" : "=v"(r) : "v"(lo), "v"(hi));
  return r;
}

// gfx950 cross-lane half-register swaps (both operands read AND written)
__device__ __forceinline__ void pl32_swap(unsigned &a, unsigned &b) {
  asm("v_permlane32_swap_b32 %0, %1" : "+v"(a), "+v"(b));
}
__device__ __forceinline__ void pl16_swap(unsigned &a, unsigned &b) {
  asm("v_permlane16_swap_b32 %0, %1" : "+v"(a), "+v"(b));
}

__device__ __forceinline__ s16x8 lds_read8(const unsigned short* p) {
  s16x8 r;
  __builtin_memcpy(&r, p, 16);
  return r;
}

// async global->LDS DMA, 16 B per lane (wave-uniform LDS base + lane*16)
__device__ __forceinline__ void async16(const unsigned short* g, unsigned short* l) {
  __builtin_amdgcn_global_load_lds(
      (const __attribute__((address_space(1))) unsigned int*)g,
      (__attribute__((address_space(3))) unsigned int*)l, 16, 0, 0);
}

// ---------------------------------------------------------------------------
// Pre-pass (unchanged, validated): one block per (head,kb).
//   K blob  (type 0): u16 idx key*64 + (d   ^ 8*(key&7))
//   V^T blob(type 1): u16 idx d*64   + (key ^ 8*(d&7))
// ---------------------------------------------------------------------------
__global__ __launch_bounds__(256) void prepack(const float* __restrict__ Kg,
                                               const float* __restrict__ Vg,
                                               unsigned short* __restrict__ ws) {
  __shared__ float vlds[BC * 65];
  const int hk = blockIdx.x;
  const int src = (hk >> 5) * (SEQ * DIM) + (hk & 31) * (BC * DIM);
  const float* kbase = Kg + src;
  const float* vbase = Vg + src;
  unsigned short* kout = ws + (hk * 2) * TILE_U16;
  unsigned short* vout = ws + (hk * 2 + 1) * TILE_U16;
  const int t = threadIdx.x;

#pragma unroll
  for (int j = 0; j < 4; ++j) {
    int o = t + 256 * j;
    int key = o >> 4;
    int d0 = 4 * (o & 15);
    float4 v = *(const float4*)(vbase + key * DIM + d0);
    __builtin_memcpy(&vlds[key * 65 + d0], &v, 16);
  }

#pragma unroll
  for (int j = 0; j < 4; ++j) {
    int o = t + 256 * j;
    int row = o >> 4;
    int d0 = (4 * (o & 15)) ^ (8 * (row & 7));
    float4 v = *(const float4*)(kbase + row * DIM + d0);
    uint2 val;
    val.x = pack2(v.x, v.y);
    val.y = pack2(v.z, v.w);
    __builtin_memcpy(kout + o * 4, &val, 8);
  }

  __syncthreads();

#pragma unroll
  for (int j = 0; j < 4; ++j) {
    int o = t + 256 * j;
    int d = o >> 4;
    int k0 = (4 * (o & 15)) ^ (8 * (d & 7));
    float a = vlds[(k0 + 0) * 65 + d];
    float b = vlds[(k0 + 1) * 65 + d];
    float e = vlds[(k0 + 2) * 65 + d];
    float f = vlds[(k0 + 3) * 65 + d];
    uint2 val;
    val.x = pack2(a, b);
    val.y = pack2(e, f);
    __builtin_memcpy(vout + o * 4, &val, 8);
  }
}

// ---------------------------------------------------------------------------
// R13: halve the phase-boundary count. All schedule variants (R1/R7/R10/R11/
// R12) pin at 92-96 us with MfmaUtil ~30% and ~65% empty issue slots; the one
// invariant is 32 iterations x the same serial phase skeleton. This version
// processes TWO 64-key sub-tiles per loop trip (16 trips, one barrier each):
//   stage(pair i+1) ; QK0 ; SM0 ; QK1 ; PV0 ; SM1 ; PV1 ; barrier
// Per-iteration fixed latency (ds_read->MFMA startup, MFMA-tail->exp2,
// permlane chain->PV, barrier skew) amortizes over 2x work, and QK1/PV0 are
// adjacent independent MFMA clusters. Dataflow = validated R1 protocol with
// double-buffered 2x16KB K + 2x16KB V (64 KB LDS, 2 blocks/CU).
// ---------------------------------------------------------------------------
__global__ __launch_bounds__(512, 4) void fattn_kernel(
    const float* __restrict__ Qg, const unsigned short* __restrict__ ws,
    float* __restrict__ Og) {
  __shared__ __align__(16) unsigned short klds[2][2 * TILE_U16];   // 2 x 16 KB
  __shared__ __align__(16) unsigned short vtlds[2][2 * TILE_U16];  // 2 x 16 KB

  const int tid = threadIdx.x;
  const int w = tid >> 6;
  const int lane = tid & 63;
  const int q = lane >> 4;  // quad
  const int c = lane & 15;  // m/n index within 16
  const int head = blockIdx.x & 63;  // head h -> XCD h%8 (L2 affinity)
  const int qblk = blockIdx.x >> 6;  // 0..7
  const int hbase = head * (SEQ * DIM);
  const int qbase = qblk * BR + w * 32;

  const float qscale = 0.18033688011112042f;  // log2(e)/sqrt(64), folded into Q

  const unsigned short* blobs = ws + head * (NB * 2 * TILE_U16);

  const int xoff0 = (q * 8) ^ ((c & 7) * 8);
  const int xoff1 = (32 + q * 8) ^ ((c & 7) * 8);

  // stage blob pair i (tiles 2i, 2i+1): 4 x async16, 8 KB each
  auto stagePair = [&](int i, int buf) {
    const unsigned short* base = blobs + (2 * i) * (2 * TILE_U16) + tid * 8;
    async16(base, &klds[buf][w * 512]);                             // K of 2i
    async16(base + TILE_U16, &vtlds[buf][w * 512]);                 // V of 2i
    async16(base + 2 * TILE_U16, &klds[buf][TILE_U16 + w * 512]);   // K of 2i+1
    async16(base + 3 * TILE_U16, &vtlds[buf][TILE_U16 + w * 512]);  // V of 2i+1
  };

  // prologue: pair 0 in flight
  stagePair(0, 0);

  // Q fragments (B operand of S^T = K.Q^T): lane holds Q[row=c+16n][d=q*8+j+32kc]
  s16x8 qf[2][2];
#pragma unroll
  for (int n = 0; n < 2; ++n) {
    const float* qp = Qg + hbase + (qbase + n * 16 + c) * DIM + q * 8;
#pragma unroll
    for (int kc = 0; kc < 2; ++kc) {
      float4 x = *(const float4*)(qp + kc * 32);
      float4 y = *(const float4*)(qp + kc * 32 + 4);
      u32x4 t = {pack2(x.x * qscale, x.y * qscale),
                 pack2(x.z * qscale, x.w * qscale),
                 pack2(y.x * qscale, y.y * qscale),
                 pack2(y.z * qscale, y.w * qscale)};
      qf[n][kc] = __builtin_bit_cast(s16x8, t);
    }
  }

  const f32x4 vzero = {0.f, 0.f, 0.f, 0.f};
  f32x4 lrun4[2] = {vzero, vzero};
  f32x4 oacc[4][2];
#pragma unroll
  for (int mt = 0; mt < 4; ++mt) {
    oacc[mt][0] = vzero;
    oacc[mt][1] = vzero;
  }

  f32x4 st[4][2];
  s16x8 pfrA[2][2], pfrB[2][2];

  // QK^T: st = K(sub-tile) . Q^T
  auto qk = [&](const unsigned short* kbuf) {
#pragma unroll
    for (int kt = 0; kt < 4; ++kt) {
      st[kt][0] = vzero;
      st[kt][1] = vzero;
    }
#pragma unroll
    for (int kc = 0; kc < 2; ++kc) {
      const int off = kc ? xoff1 : xoff0;
#pragma unroll
      for (int kt = 0; kt < 4; ++kt) {
        s16x8 kf = lds_read8(&kbuf[(c + 16 * kt) * 64 + off]);
        st[kt][0] = __builtin_amdgcn_mfma_f32_16x16x32_bf16(kf, qf[0][kc], st[kt][0], 0, 0, 0);
        st[kt][1] = __builtin_amdgcn_mfma_f32_16x16x32_bf16(kf, qf[1][kc], st[kt][1], 0, 0, 0);
      }
    }
  };

  // softmax: exp2(st) + l accumulate + in-register quad transpose -> pfr
  auto sm = [&](s16x8 (&pfr)[2][2]) {
#pragma unroll
    for (int n = 0; n < 2; ++n) {
#pragma unroll
      for (int kt = 0; kt < 4; ++kt)
#pragma unroll
        for (int r = 0; r < 4; ++r)
          st[kt][n][r] = __builtin_amdgcn_exp2f(st[kt][n][r]);
      lrun4[n] += (st[0][n] + st[1][n]) + (st[2][n] + st[3][n]);

      unsigned w00 = cvt_pk_bf16(st[0][n][0], st[0][n][1]);
      unsigned w10 = cvt_pk_bf16(st[1][n][0], st[1][n][1]);
      unsigned w20 = cvt_pk_bf16(st[2][n][0], st[2][n][1]);
      unsigned w30 = cvt_pk_bf16(st[3][n][0], st[3][n][1]);
      unsigned w01 = cvt_pk_bf16(st[0][n][2], st[0][n][3]);
      unsigned w11 = cvt_pk_bf16(st[1][n][2], st[1][n][3]);
      unsigned w21 = cvt_pk_bf16(st[2][n][2], st[2][n][3]);
      unsigned w31 = cvt_pk_bf16(st[3][n][2], st[3][n][3]);
      pl32_swap(w00, w10);
      pl32_swap(w20, w30);
      pl32_swap(w01, w11);
      pl32_swap(w21, w31);
      pl16_swap(w00, w10);
      pl16_swap(w20, w30);
      pl16_swap(w01, w11);
      pl16_swap(w21, w31);
      u32x4 f0 = {w00, w01, w10, w11};
      u32x4 f1 = {w20, w21, w30, w31};
      pfr[n][0] = __builtin_bit_cast(s16x8, f0);
      pfr[n][1] = __builtin_bit_cast(s16x8, f1);
    }
  };

  // O^T += V^T(sub-tile) . P^T
  auto pv = [&](const unsigned short* vbuf, const s16x8 (&pfr)[2][2]) {
#pragma unroll
    for (int kc = 0; kc < 2; ++kc) {
      const int off = kc ? xoff1 : xoff0;
#pragma unroll
      for (int mt = 0; mt < 4; ++mt) {
        s16x8 vf = lds_read8(&vbuf[(c + 16 * mt) * 64 + off]);
        oacc[mt][0] = __builtin_amdgcn_mfma_f32_16x16x32_bf16(vf, pfr[0][kc], oacc[mt][0], 0, 0, 0);
        oacc[mt][1] = __builtin_amdgcn_mfma_f32_16x16x32_bf16(vf, pfr[1][kc], oacc[mt][1], 0, 0, 0);
      }
    }
  };

  __syncthreads();  // drains pair-0 DMA (vmcnt(0)) + barrier

  // one loop trip: 128 keys from buffer b; stages pair i+1 into b^1.
  auto body = [&](int i, int b) {
    if (i + 1 < NPAIR) stagePair(i + 1, b ^ 1);
    qk(klds[b]);                        // sub-tile 0 (keys 0..63)
    sm(pfrA);
    qk(klds[b] + TILE_U16);             // sub-tile 1 (keys 64..127)
    pv(vtlds[b], pfrA);                 // independent of qk(sub1) -> overlap
    sm(pfrB);
    pv(vtlds[b] + TILE_U16, pfrB);
    // barrier: (a) pair i+1's DMA drained (had the whole trip to land),
    // (b) all waves done reading buffer b before trip i+2 overwrites it.
    __syncthreads();
  };

#pragma unroll 2
  for (int i = 0; i < NPAIR; ++i) body(i, i & 1);

  // ---- epilogue: reduce l (4 lanes of lrun4, then across quads), O = O^T / l
#pragma unroll
  for (int n = 0; n < 2; ++n) {
    f32x4 l4 = lrun4[n];
    float l = (l4.x + l4.y) + (l4.z + l4.w);
    l += __shfl_xor(l, 16);
    l += __shfl_xor(l, 32);
    float inv = 1.0f / l;
    int row = qbase + 16 * n + c;
#pragma unroll
    for (int mt = 0; mt < 4; ++mt) {
      f32x4 r = oacc[mt][n] * inv;
      *(f32x4*)(Og + hbase + row * DIM + 16 * mt + 4 * q) = r;
    }
  }
}

extern "C" void kernel_launch(void* const* d_in, const int* in_sizes, int n_in,
                              void* d_out, int out_size, void* d_ws, size_t ws_size,
                              hipStream_t stream) {
  const float* Q = (const float*)d_in[0];
  const float* K = (const float*)d_in[1];
  const float* V = (const float*)d_in[2];
  float* O = (float*)d_out;
  unsigned short* ws = (unsigned short*)d_ws;  // needs 32 MiB
  hipLaunchKernelGGL(prepack, dim3(HEADS * NB), dim3(256), 0, stream, K, V, ws);
  hipLaunchKernelGGL(fattn_kernel, dim3(HEADS * (SEQ / BR)), dim3(512), 0, stream,
                     Q, (const unsigned short*)ws, O);
}

// Round 9
// 197.931 us; speedup vs baseline: 1.1144x; 1.1144x over previous
//
#include <hip/hip_runtime.h>

#define HEADS 64
#define SEQ 2048
#define DIM 64
#define BR 256          // q rows per block (64 per wave, 4 waves)
#define BC 64           // keys per tile
#define NB (SEQ / BC)   // 32 tiles
#define TILE_U16 (BC * DIM)  // 4096 u16 = 8192 B per blob

typedef __attribute__((ext_vector_type(4))) float f32x4;
typedef __attribute__((ext_vector_type(8))) short s16x8;
typedef __attribute__((ext_vector_type(4))) unsigned int u32x4;

// pack two fp32 -> two bf16 (round-half-up) in one v_perm
__device__ __forceinline__ unsigned pack2(float lo, float hi) {
  unsigned a = __builtin_bit_cast(unsigned, hi) + 0x8000u;
  unsigned b = __builtin_bit_cast(unsigned, lo) + 0x8000u;
  return __builtin_amdgcn_perm(a, b, 0x07060302u);
}

// single-instruction packed fp32->bf16 (RNE)
__device__ __forceinline__ unsigned cvt_pk_bf16(float lo, float hi) {
  unsigned r;
  asm("v_cvt_pk_bf16_f32 %0, %1, %2" : "=v"(r) : "v"(lo), "v"(hi));
  return r;
}

// gfx950 cross-lane half-register swaps (both operands read AND written)
__device__ __forceinline__ void pl32_swap(unsigned &a, unsigned &b) {
  asm("v_permlane32_swap_b32 %0, %1" : "+v"(a), "+v"(b));
}
__device__ __forceinline__ void pl16_swap(unsigned &a, unsigned &b) {
  asm("v_permlane16_swap_b32 %0, %1" : "+v"(a), "+v"(b));
}

__device__ __forceinline__ s16x8 lds_read8(const unsigned short* p) {
  s16x8 r;
  __builtin_memcpy(&r, p, 16);
  return r;
}

// async global->LDS DMA, 16 B per lane (wave-uniform LDS base + lane*16)
__device__ __forceinline__ void async16(const unsigned short* g, unsigned short* l) {
  __builtin_amdgcn_global_load_lds(
      (const __attribute__((address_space(1))) unsigned int*)g,
      (__attribute__((address_space(3))) unsigned int*)l, 16, 0, 0);
}

// ---------------------------------------------------------------------------
// Pre-pass (unchanged, validated): one block per (head,kb).
//   K blob  (type 0): u16 idx key*64 + (d   ^ 8*(key&7))
//   V^T blob(type 1): u16 idx d*64   + (key ^ 8*(d&7))
// ---------------------------------------------------------------------------
__global__ __launch_bounds__(256) void prepack(const float* __restrict__ Kg,
                                               const float* __restrict__ Vg,
                                               unsigned short* __restrict__ ws) {
  __shared__ float vlds[BC * 65];
  const int hk = blockIdx.x;
  const int src = (hk >> 5) * (SEQ * DIM) + (hk & 31) * (BC * DIM);
  const float* kbase = Kg + src;
  const float* vbase = Vg + src;
  unsigned short* kout = ws + (hk * 2) * TILE_U16;
  unsigned short* vout = ws + (hk * 2 + 1) * TILE_U16;
  const int t = threadIdx.x;

#pragma unroll
  for (int j = 0; j < 4; ++j) {
    int o = t + 256 * j;
    int key = o >> 4;
    int d0 = 4 * (o & 15);
    float4 v = *(const float4*)(vbase + key * DIM + d0);
    __builtin_memcpy(&vlds[key * 65 + d0], &v, 16);
  }

#pragma unroll
  for (int j = 0; j < 4; ++j) {
    int o = t + 256 * j;
    int row = o >> 4;
    int d0 = (4 * (o & 15)) ^ (8 * (row & 7));
    float4 v = *(const float4*)(kbase + row * DIM + d0);
    uint2 val;
    val.x = pack2(v.x, v.y);
    val.y = pack2(v.z, v.w);
    __builtin_memcpy(kout + o * 4, &val, 8);
  }

  __syncthreads();

#pragma unroll
  for (int j = 0; j < 4; ++j) {
    int o = t + 256 * j;
    int d = o >> 4;
    int k0 = (4 * (o & 15)) ^ (8 * (d & 7));
    float a = vlds[(k0 + 0) * 65 + d];
    float b = vlds[(k0 + 1) * 65 + d];
    float e = vlds[(k0 + 2) * 65 + d];
    float f = vlds[(k0 + 3) * 65 + d];
    uint2 val;
    val.x = pack2(a, b);
    val.y = pack2(e, f);
    __builtin_memcpy(vout + o * 4, &val, 8);
  }
}

// ---------------------------------------------------------------------------
// R14: fat waves (AITER-style 256-VGPR, m243). Evidence: no pipe >30% busy,
// occupancy can't rise (R11), barriers/DMA/interleave all null (R7/R12) ->
// waves are individually latency-starved (each issues ~15% of cycles) and
// thin (64 VGPR, one dependent stream). This version: 64 q-rows per wave
// (4 independent 16-row streams), 4-wave blocks, grid 512, ~210 VGPR at
// __launch_bounds__(256,2). Each kf/vf ds_read feeds 4 independent MFMAs
// (per-work LDS traffic -33%), and the wave always has 4 independent chains
// to interleave. Dataflow = validated straight per-tile double-buffer.
// Spill guard: WRITE_SIZE must stay ~33 MB (R13's spill showed as 166 MB).
// ---------------------------------------------------------------------------
__global__ __launch_bounds__(256, 2) void fattn_kernel(
    const float* __restrict__ Qg, const unsigned short* __restrict__ ws,
    float* __restrict__ Og) {
  __shared__ __align__(16) unsigned short klds[2][TILE_U16];   // 2 x 8 KB
  __shared__ __align__(16) unsigned short vtlds[2][TILE_U16];  // 2 x 8 KB

  const int tid = threadIdx.x;
  const int w = tid >> 6;            // 0..3
  const int lane = tid & 63;
  const int q = lane >> 4;  // quad
  const int c = lane & 15;  // m/n index within 16
  const int head = blockIdx.x & 63;  // head h -> XCD h%8 (L2 affinity)
  const int qblk = blockIdx.x >> 6;  // 0..7
  const int hbase = head * (SEQ * DIM);
  const int qbase = qblk * BR + w * 64;  // 64 rows per wave

  const float qscale = 0.18033688011112042f;  // log2(e)/sqrt(64), folded into Q

  const unsigned short* blobs = ws + head * (NB * 2 * TILE_U16);

  const int xoff0 = (q * 8) ^ ((c & 7) * 8);
  const int xoff1 = (32 + q * 8) ^ ((c & 7) * 8);

  // 256 threads stage one 8 KB blob in two async16 sweeps
  auto stageK = [&](int t, unsigned short* dst) {
    const unsigned short* src = blobs + t * (2 * TILE_U16) + tid * 8;
    unsigned short* d = dst + w * 512;
    async16(src, d);
    async16(src + 2048, d + 2048);
  };
  auto stageV = [&](int t, unsigned short* dst) {
    const unsigned short* src = blobs + t * (2 * TILE_U16) + TILE_U16 + tid * 8;
    unsigned short* d = dst + w * 512;
    async16(src, d);
    async16(src + 2048, d + 2048);
  };

  // issue tile-0 DMA into buffer 0
  stageK(0, klds[0]);
  stageV(0, vtlds[0]);

  // Q fragments: 4 row-groups (64 rows). lane holds Q[row=c+16n][d=q*8+j+32kc]
  s16x8 qf[4][2];
#pragma unroll
  for (int n = 0; n < 4; ++n) {
    const float* qp = Qg + hbase + (qbase + n * 16 + c) * DIM + q * 8;
#pragma unroll
    for (int kc = 0; kc < 2; ++kc) {
      float4 x = *(const float4*)(qp + kc * 32);
      float4 y = *(const float4*)(qp + kc * 32 + 4);
      u32x4 t = {pack2(x.x * qscale, x.y * qscale),
                 pack2(x.z * qscale, x.w * qscale),
                 pack2(y.x * qscale, y.y * qscale),
                 pack2(y.z * qscale, y.w * qscale)};
      qf[n][kc] = __builtin_bit_cast(s16x8, t);
    }
  }

  const f32x4 vzero = {0.f, 0.f, 0.f, 0.f};
  f32x4 lrun4[4] = {vzero, vzero, vzero, vzero};
  f32x4 oacc[4][4];  // [mt][n]
#pragma unroll
  for (int mt = 0; mt < 4; ++mt)
#pragma unroll
    for (int n = 0; n < 4; ++n) oacc[mt][n] = vzero;

  __syncthreads();  // drains tile-0 DMA (vmcnt(0)) + barrier

  for (int kb = 0; kb < NB; ++kb) {
    const int p = kb & 1;

    if (kb + 1 < NB) {
      stageK(kb + 1, klds[p ^ 1]);
      stageV(kb + 1, vtlds[p ^ 1]);
    }

    // 1) S^T = K . Q^T for 4 row-groups: each kf read feeds 4 MFMAs
    f32x4 st[4][4];  // [kt][n]
#pragma unroll
    for (int kt = 0; kt < 4; ++kt)
#pragma unroll
      for (int n = 0; n < 4; ++n) st[kt][n] = vzero;
#pragma unroll
    for (int kc = 0; kc < 2; ++kc) {
      const int off = kc ? xoff1 : xoff0;
#pragma unroll
      for (int kt = 0; kt < 4; ++kt) {
        s16x8 kf = lds_read8(&klds[p][(c + 16 * kt) * 64 + off]);
#pragma unroll
        for (int n = 0; n < 4; ++n)
          st[kt][n] = __builtin_amdgcn_mfma_f32_16x16x32_bf16(kf, qf[n][kc], st[kt][n], 0, 0, 0);
      }
    }

    // 2) softmax per row-group: exp2, l accumulate, quad transpose -> pfr
    s16x8 pfr[4][2];  // [n][kc]
#pragma unroll
    for (int n = 0; n < 4; ++n) {
#pragma unroll
      for (int kt = 0; kt < 4; ++kt)
#pragma unroll
        for (int r = 0; r < 4; ++r)
          st[kt][n][r] = __builtin_amdgcn_exp2f(st[kt][n][r]);
      lrun4[n] += (st[0][n] + st[1][n]) + (st[2][n] + st[3][n]);

      unsigned w00 = cvt_pk_bf16(st[0][n][0], st[0][n][1]);
      unsigned w10 = cvt_pk_bf16(st[1][n][0], st[1][n][1]);
      unsigned w20 = cvt_pk_bf16(st[2][n][0], st[2][n][1]);
      unsigned w30 = cvt_pk_bf16(st[3][n][0], st[3][n][1]);
      unsigned w01 = cvt_pk_bf16(st[0][n][2], st[0][n][3]);
      unsigned w11 = cvt_pk_bf16(st[1][n][2], st[1][n][3]);
      unsigned w21 = cvt_pk_bf16(st[2][n][2], st[2][n][3]);
      unsigned w31 = cvt_pk_bf16(st[3][n][2], st[3][n][3]);
      // stage 1: reg-bit0 <-> lane-bit1 (32-lane halves)
      pl32_swap(w00, w10);
      pl32_swap(w20, w30);
      pl32_swap(w01, w11);
      pl32_swap(w21, w31);
      // stage 2: reg-bit0 <-> lane-bit0 (16-lane quads)
      pl16_swap(w00, w10);
      pl16_swap(w20, w30);
      pl16_swap(w01, w11);
      pl16_swap(w21, w31);
      u32x4 f0 = {w00, w01, w10, w11};
      u32x4 f1 = {w20, w21, w30, w31};
      pfr[n][0] = __builtin_bit_cast(s16x8, f0);
      pfr[n][1] = __builtin_bit_cast(s16x8, f1);
    }

    // 3) O^T += V^T . P^T: each vf read feeds 4 MFMAs
#pragma unroll
    for (int kc = 0; kc < 2; ++kc) {
      const int off = kc ? xoff1 : xoff0;
#pragma unroll
      for (int mt = 0; mt < 4; ++mt) {
        s16x8 vf = lds_read8(&vtlds[p][(c + 16 * mt) * 64 + off]);
#pragma unroll
        for (int n = 0; n < 4; ++n)
          oacc[mt][n] = __builtin_amdgcn_mfma_f32_16x16x32_bf16(vf, pfr[n][kc], oacc[mt][n], 0, 0, 0);
      }
    }

    // barrier: (a) next-tile DMA drained (vmcnt(0) implied), (b) all waves done
    // reading buf p before iter kb+1's DMA overwrites it.
    __syncthreads();
  }

  // ---- epilogue: reduce l (4 lanes of lrun4, then across quads), O = O^T / l
#pragma unroll
  for (int n = 0; n < 4; ++n) {
    f32x4 l4 = lrun4[n];
    float l = (l4.x + l4.y) + (l4.z + l4.w);
    l += __shfl_xor(l, 16);
    l += __shfl_xor(l, 32);
    float inv = 1.0f / l;
    int row = qbase + 16 * n + c;
#pragma unroll
    for (int mt = 0; mt < 4; ++mt) {
      f32x4 r = oacc[mt][n] * inv;
      *(f32x4*)(Og + hbase + row * DIM + 16 * mt + 4 * q) = r;
    }
  }
}

extern "C" void kernel_launch(void* const* d_in, const int* in_sizes, int n_in,
                              void* d_out, int out_size, void* d_ws, size_t ws_size,
                              hipStream_t stream) {
  const float* Q = (const float*)d_in[0];
  const float* K = (const float*)d_in[1];
  const float* V = (const float*)d_in[2];
  float* O = (float*)d_out;
  unsigned short* ws = (unsigned short*)d_ws;  // needs 32 MiB
  hipLaunchKernelGGL(prepack, dim3(HEADS * NB), dim3(256), 0, stream, K, V, ws);
  hipLaunchKernelGGL(fattn_kernel, dim3(HEADS * (SEQ / BR)), dim3(256), 0, stream,
                     Q, (const unsigned short*)ws, O);
}